// Round 6
// baseline (277.447 us; speedup 1.0000x reference)
//
#include <hip/hip_runtime.h>
#include <math.h>

#define NATOMS 4096
#define R_CUT 5.0f
#define BLOCK 256

// clang-native vectors (HIP float4 is a struct)
typedef float f4 __attribute__((ext_vector_type(4)));
typedef float f3 __attribute__((ext_vector_type(3), aligned(4)));

// ---------------- K1: zero the entire output ----------------
// disp [N,N,3] f32 followed by mask [N,N] f32 is one contiguous
// 16*N*N = 268,435,456-byte region. Grid-stride dwordx4 sweep --
// structurally identical to the rocclr fill that hits 6.6 TB/s.
__global__ __launch_bounds__(BLOCK) void zero_kernel(f4* __restrict__ out, int n16)
{
    const int stride = (int)gridDim.x * BLOCK;
    int idx = (int)blockIdx.x * BLOCK + (int)threadIdx.x;
    const f4 z = {0.0f, 0.0f, 0.0f, 0.0f};
    for (; idx < n16; idx += stride)
        out[idx] = z;
}

// ---------------- K2: compute + sparse store ----------------
// Only ~34 of 4096 columns per row are same-batch AND within cutoff
// (98.4% of the output is zero, already written by K1). Store only
// where m is true: ~137K pairs -> ~20 MB scattered traffic.
__global__ __launch_bounds__(BLOCK) void sparse_kernel(
    const float* __restrict__ pos,    // [N,3]
    const float* __restrict__ cell,   // [B,3,3]
    const int*   __restrict__ batch,  // [N]
    float* __restrict__ disp_out,     // [N,N,3]
    float* __restrict__ mask_out)     // [N,N]
{
    const int i   = (int)blockIdx.x;          // one row per block
    const int tid = (int)threadIdx.x;

    // Row-uniform data: scalar loads; redundant 3x3 inverse per thread.
    const int bi = batch[i];
    const float pix = pos[i * 3 + 0];
    const float piy = pos[i * 3 + 1];
    const float piz = pos[i * 3 + 2];

    const float* C = cell + (size_t)bi * 9;
    const float C00 = C[0], C01 = C[1], C02 = C[2];
    const float C10 = C[3], C11 = C[4], C12 = C[5];
    const float C20 = C[6], C21 = C[7], C22 = C[8];
    // A = inv(C^T) = cofactor(C) / det(C)
    const float cof00 =  (C11 * C22 - C12 * C21);
    const float cof01 = -(C10 * C22 - C12 * C20);
    const float cof02 =  (C10 * C21 - C11 * C20);
    const float cof10 = -(C01 * C22 - C02 * C21);
    const float cof11 =  (C00 * C22 - C02 * C20);
    const float cof12 = -(C00 * C21 - C01 * C20);
    const float cof20 =  (C01 * C12 - C02 * C11);
    const float cof21 = -(C00 * C12 - C02 * C10);
    const float cof22 =  (C00 * C11 - C01 * C10);
    const float det = C00 * cof00 + C01 * cof01 + C02 * cof02;
    const float id  = 1.0f / det;
    const float A00 = cof00 * id, A01 = cof01 * id, A02 = cof02 * id;
    const float A10 = cof10 * id, A11 = cof11 * id, A12 = cof12 * id;
    const float A20 = cof20 * id, A21 = cof21 * id, A22 = cof22 * id;

    const size_t rowm = (size_t)i * NATOMS;
    const size_t rowd = rowm * 3;

    #pragma unroll 4
    for (int k = 0; k < NATOMS / BLOCK; ++k) {
        const int j = k * BLOCK + tid;

        // cheap reject first: different graph -> nothing to write
        const int bjv = batch[j];
        if (bjv != bi) continue;

        const float pjx = pos[j * 3 + 0];
        const float pjy = pos[j * 3 + 1];
        const float pjz = pos[j * 3 + 2];

        // raw displacement, exact-order f32 (matches numpy, no fma contraction)
        const float d0 = __fsub_rn(pix, pjx);
        const float d1 = __fsub_rn(piy, pjy);
        const float d2 = __fsub_rn(piz, pjz);

        // scaled = inv(cell^T) @ d
        const float s0 = __fadd_rn(__fadd_rn(__fmul_rn(A00, d0), __fmul_rn(A01, d1)), __fmul_rn(A02, d2));
        const float s1 = __fadd_rn(__fadd_rn(__fmul_rn(A10, d0), __fmul_rn(A11, d1)), __fmul_rn(A12, d2));
        const float s2 = __fadd_rn(__fadd_rn(__fmul_rn(A20, d0), __fmul_rn(A21, d1)), __fmul_rn(A22, d2));

        const float r0 = rintf(s0);   // round-half-even == jnp.round
        const float r1 = rintf(s1);
        const float r2 = rintf(s2);

        // wrapped = d - cell @ r, exact numpy order, no contraction
        const float w0 = __fsub_rn(d0, __fadd_rn(__fadd_rn(__fmul_rn(C00, r0), __fmul_rn(C01, r1)), __fmul_rn(C02, r2)));
        const float w1 = __fsub_rn(d1, __fadd_rn(__fadd_rn(__fmul_rn(C10, r0), __fmul_rn(C11, r1)), __fmul_rn(C12, r2)));
        const float w2 = __fsub_rn(d2, __fadd_rn(__fadd_rn(__fmul_rn(C20, r0), __fmul_rn(C21, r1)), __fmul_rn(C22, r2)));

        const float n2 = __fadd_rn(__fadd_rn(__fmul_rn(w0, w0), __fmul_rn(w1, w1)), __fmul_rn(w2, w2));
        const bool m = (i != j) && (sqrtf(n2) < R_CUT);

        if (m) {
            f3 v; v.x = w0; v.y = w1; v.z = w2;
            *(f3*)(disp_out + rowd + (size_t)j * 3) = v;   // dwordx3, 12B-aligned
            mask_out[rowm + (size_t)j] = 1.0f;
        }
    }
}

extern "C" void kernel_launch(void* const* d_in, const int* in_sizes, int n_in,
                              void* d_out, int out_size, void* d_ws, size_t ws_size,
                              hipStream_t stream) {
    const float* pos   = (const float*)d_in[0];
    const float* cell  = (const float*)d_in[1];
    const int*   batch = (const int*)d_in[2];

    float* disp_out = (float*)d_out;
    float* mask_out = (float*)d_out + (size_t)NATOMS * NATOMS * 3;

    // K1: zero disp+mask (contiguous 16*N*N bytes = 16,777,216 float4s)
    const int n16 = (NATOMS / 4) * NATOMS * 4;   // 16,777,216
    zero_kernel<<<2048, BLOCK, 0, stream>>>((f4*)d_out, n16);

    // K2: stream-ordered after K1; writes only the ~1.6% nonzero entries
    sparse_kernel<<<NATOMS, BLOCK, 0, stream>>>(pos, cell, batch, disp_out, mask_out);
}